// Round 21
// baseline (336.620 us; speedup 1.0000x reference)
//
#include <hip/hip_runtime.h>

// ChemicalLLM: x_{t+1} = norm(relu(x + a*einsum(W,x,x))), then big decode GEMM.
//  R20 (282.6, best): XCD swizzle +10us on decode; decode now ~215us vs
//  ~160us write floor. Ledger: prep 10, recur 35, decode 215, gaps 15.
//  R21 single change: decode stores PLAIN (through-L2) instead of NT.
//  Rationale: NT bypasses L2 -> each 512B chunk hits HBM as-is; the fill
//  kernel (6.7-6.9 TB/s) writes through L2, letting it aggregate bursts.
//  NT was never isolated-tested (R8 bundled it). XCD-partitioned reads
//  (1.5MiB/XCD) leave ~2.5MiB L2 slack to absorb the write stream.
//  Everything else = R20 verbatim.

typedef unsigned int u32;
typedef unsigned short u16;
typedef __attribute__((ext_vector_type(8))) short short8;
typedef __attribute__((ext_vector_type(4))) float f32x4;
typedef __attribute__((ext_vector_type(4))) int i32x4;

#define DECAY_ 0.1f
#define ALPHA_ 0.2f
#define EPS_ 1e-8f
#define B_ 8
#define S_ 1024
#define N_ 64
#define V_ 32000
#define NCHUNK_ 32
#define CHUNK_ 32
#define WARM_ 8
#define DEPTH_ (CHUNK_ + WARM_)  // 40
#define UBOUND_ 0.45f   // bound on max|W+W^T| (~0.35 actual; +-127 clamp guards tails)
#define NUNITS_ 288     // sum_j ((j>>3)+1) 8-byte units per k
#define UQ_DWORDS_ (NUNITS_ * 64 * 2)  // 36864 dwords = 147456 B

// ---------- bf16 helpers (manual, RNE) ----------
static __device__ __forceinline__ u16 f2bf(float f) {
  u32 u = __float_as_uint(f);
  u32 r = (u + 0x7fffu + ((u >> 16) & 1u)) >> 16;
  return (u16)r;
}

// ---------- int8 dot4 ----------
#if defined(__has_builtin)
#if __has_builtin(__builtin_amdgcn_sdot4)
#define HAVE_SDOT4 1
#endif
#endif
static __device__ __forceinline__ int dot4(int a, int b, int c) {
#ifdef HAVE_SDOT4
  return __builtin_amdgcn_sdot4(a, b, c, false);
#else
  int s = c;
  s += (int)(signed char)(a) * (int)(signed char)(b);
  s += (int)(signed char)(a >> 8) * (int)(signed char)(b >> 8);
  s += (int)(signed char)(a >> 16) * (int)(signed char)(b >> 16);
  s += (int)(a >> 24) * (int)(b >> 24);
  return s;
#endif
}

static __device__ __forceinline__ float wave_max64(float v) {
#pragma unroll
  for (int m = 1; m < 64; m <<= 1) v = fmaxf(v, __shfl_xor(v, m, 64));
  return v;
}

// ---------- prep (fused): Wd -> bf16 (all blocks) + symmetrized W quant (blocks<64) ----------
__global__ void prep_kernel(const float* __restrict__ Wd, u16* __restrict__ wdb,
                            const float* __restrict__ W, u32* __restrict__ Uq) {
  int idx = blockIdx.x * blockDim.x + threadIdx.x;  // 8000*256 = 2048000
  wdb[idx] = f2bf(Wd[idx]);
  if (blockIdx.x < 64) {
    const int j = blockIdx.x;
    const int m = j >> 3;
    const int off8 = j + 4 * m * (m - 1) + (j & 7) * m;
    const int cnt = 2 * (m + 1) * 64;  // dwords for this j
    const float s = 127.0f / UBOUND_;
    for (int d = threadIdx.x; d < cnt; d += 256) {
      int q4 = d >> 6;   // dword-in-column: i = 4*q4 + e
      int k = d & 63;
      u32 pk = 0;
#pragma unroll
      for (int e = 0; e < 4; ++e) {
        int i = 4 * q4 + e;
        float v = 0.0f;
        if (i < j)
          v = W[((size_t)i * N_ + j) * N_ + k] + W[((size_t)j * N_ + i) * N_ + k];
        else if (i == j)
          v = W[((size_t)j * N_ + j) * N_ + k];
        int qi = (int)rintf(v * s);
        qi = qi > 127 ? 127 : (qi < -127 ? -127 : qi);
        pk |= ((u32)qi & 0xffu) << (8 * e);
      }
      int dst = 2 * ((off8 + (q4 >> 1)) * 64 + k) + (q4 & 1);
      Uq[dst] = pk;
    }
  }
}

// ---------- recurrence: grid (NCHUNK, B), 512 threads (8 waves, 2/SIMD) ----------
__global__ __launch_bounds__(512, 2) void recur_kernel(
    const int* __restrict__ ids, const float* __restrict__ emb,
    const u32* __restrict__ Uq,
    u16* __restrict__ hs, float* __restrict__ outHT) {
  const int b = blockIdx.y;
  const int chunk = blockIdx.x;
  const int lane = threadIdx.x & 63;  // k in dot phase
  const int w = threadIdx.x >> 6;     // wave 0..7, owns j in {w+8m}

  const int t0 = chunk * CHUNK_;                 // first step this chunk OWNS
  const int ts = (chunk == 0) ? 0 : t0 - WARM_;  // warmup start (h=0 IC exact at t=0)
  const int tend = t0 + CHUNK_;
  const int len = tend - ts;                     // 32 (chunk 0) or 40

  __shared__ int2 lw2[NUNITS_ * 64];  // 144 KB: ALL of W (triangular symmetrized)
  __shared__ float part[2][8][64];    // double-buffered raw partials (4 KB)
  __shared__ float erow[DEPTH_][64];  // relu'd emb rows; DEAD PREFIX reused as u16 h-rows
  __shared__ float emax[DEPTH_];      // their maxes

  const float sW = UBOUND_ * (1.0f / 127.0f);

  {
    const i32x4* src = (const i32x4*)Uq;
    i32x4* dst = (i32x4*)lw2;
    for (int ii = threadIdx.x; ii < UQ_DWORDS_ / 4; ii += 512) dst[ii] = src[ii];
  }
  for (int r = w; r < len; r += 8) {
    int id = ids[b * S_ + ts + r];
    float v = fmaxf(emb[(size_t)id * N_ + lane], 0.0f);
    erow[r][lane] = v;
    float m = wave_max64(v);
    if (lane == 0) emax[r] = m;
  }
  __syncthreads();

  float xk, smul;
  u32 pk;
  {
    xk = erow[0][lane];
    float bnd = fmaxf(emax[0], 1e-20f);
    smul = bnd * (1.0f / 127.0f) * sW;
    float inv = 127.0f / bnd;
    float u = xk * inv;
    float u0 = __shfl(u, (lane & 15) * 4 + 0, 64);
    float u1 = __shfl(u, (lane & 15) * 4 + 1, 64);
    float u2 = __shfl(u, (lane & 15) * 4 + 2, 64);
    float u3 = __shfl(u, (lane & 15) * 4 + 3, 64);
    pk = (u32)(int)rintf(u0) | ((u32)(int)rintf(u1) << 8) |
         ((u32)(int)rintf(u2) << 16) | ((u32)(int)rintf(u3) << 24);
  }

  for (int t = ts; t < tend; ++t) {
    const int sidx = t - ts;
    int xr[16];
#pragma unroll
    for (int q = 0; q < 16; ++q) xr[q] = __builtin_amdgcn_readlane((int)pk, q);
    float pf = 0.0f;
#pragma unroll
    for (int m = 0; m < 8; ++m) {
      const int j = w + 8 * m;
      const int off8 = j + 4 * m * (m - 1) + w * m;
      int a = 0;
#pragma unroll
      for (int u = 0; u <= m; ++u) {
        int2 v = lw2[(off8 + u) * 64 + lane];
        a = dot4(xr[2 * u], v.x, a);
        a = dot4(xr[2 * u + 1], v.y, a);
      }
      float xj = __uint_as_float(
          __builtin_amdgcn_readlane(__float_as_uint(xk), j));
      pf += (float)a * xj;
    }
    part[t & 1][w][lane] = pf;
    __syncthreads();

    float iact = 0.0f;
#pragma unroll
    for (int q = 0; q < 8; ++q) iact += part[t & 1][q][lane];
    float xact = fmaxf(fmaf(ALPHA_ * smul, iact, xk), 0.0f);
    float s = xact;
#pragma unroll
    for (int m = 1; m < 64; m <<= 1) s += __shfl_xor(s, m, 64);
    float rS = 1.0f / (s + EPS_);
    float h = xact * rS;

    if (w == 0 && t >= t0) {
      ((u16*)&erow[t - t0][0])[lane] = f2bf(h);
      if (t == S_ - 1) outHT[b * N_ + lane] = h;
    }

    int nidx = (sidx + 1 < len) ? sidx + 1 : len - 1;
    float pcur = erow[nidx][lane];
    float xn = fmaf(1.0f - DECAY_, h, pcur);
    float nbnd = (1.0f - DECAY_) + emax[nidx];
    float inv = 127.0f / nbnd;
    float u = xn * inv;
    float u0 = __shfl(u, (lane & 15) * 4 + 0, 64);
    float u1 = __shfl(u, (lane & 15) * 4 + 1, 64);
    float u2 = __shfl(u, (lane & 15) * 4 + 2, 64);
    float u3 = __shfl(u, (lane & 15) * 4 + 3, 64);
    pk = (u32)(int)rintf(u0) | ((u32)(int)rintf(u1) << 8) |
         ((u32)(int)rintf(u2) << 16) | ((u32)(int)rintf(u3) << 24);
    smul = nbnd * (1.0f / 127.0f) * sW;
    xk = xn;
  }

  __syncthreads();
  {
    int r = threadIdx.x >> 4;
    int l4 = (threadIdx.x & 15) * 4;
    uint2 v = *(const uint2*)((const u16*)&erow[r][0] + l4);
    *(uint2*)(hs + ((size_t)b * S_ + t0 + r) * N_ + l4) = v;
  }
}

// ---------- decode: R20 body, PLAIN stores (through-L2) ----------
__global__ __launch_bounds__(512, 2) void decode_kernel(
    const u16* __restrict__ hs, const u16* __restrict__ wd,
    const float* __restrict__ bd, float* __restrict__ out) {
  const int bid = blockIdx.x;
  const int xcd = bid & 7;
  const int rank = bid >> 3;              // 0..1999
  const int orig = xcd * 2000 + rank;     // n-major: orig = nblk*64 + mblk
  const int n0 = (orig >> 6) * 128;
  const int m0 = (orig & 63) * 128;

  const int lane = threadIdx.x & 63;
  const int w = threadIdx.x >> 6;
  const int wm = w >> 2, wn = w & 3;
  const int nw = n0 + wn * 32;
  const int mw = m0 + wm * 64;
  const int kg = (lane >> 4) * 8;
  const int rl = lane & 15;
  const int g = lane >> 4;

  __shared__ float tile[128][132];

  short8 bfr[2][2];
#pragma unroll
  for (int nt = 0; nt < 2; ++nt) {
    int v = nw + nt * 16 + rl;
#pragma unroll
    for (int ks = 0; ks < 2; ++ks)
      bfr[nt][ks] = *(const short8*)(wd + (size_t)v * N_ + ks * 32 + kg);
  }
  short8 a[4][2];
#pragma unroll
  for (int mt = 0; mt < 4; ++mt) {
    int row = mw + mt * 16 + rl;
#pragma unroll
    for (int ks = 0; ks < 2; ++ks)
      a[mt][ks] = *(const short8*)(hs + (size_t)row * N_ + ks * 32 + kg);
  }
  f32x4 acc[4][2];
#pragma unroll
  for (int nt = 0; nt < 2; ++nt) {
    float bdv = bd[nw + nt * 16 + rl];
#pragma unroll
    for (int mt = 0; mt < 4; ++mt) acc[mt][nt] = {bdv, bdv, bdv, bdv};
  }
#pragma unroll
  for (int mt = 0; mt < 4; ++mt)
#pragma unroll
    for (int nt = 0; nt < 2; ++nt) {
      acc[mt][nt] =
          __builtin_amdgcn_mfma_f32_16x16x32_bf16(a[mt][0], bfr[nt][0], acc[mt][nt], 0, 0, 0);
      acc[mt][nt] =
          __builtin_amdgcn_mfma_f32_16x16x32_bf16(a[mt][1], bfr[nt][1], acc[mt][nt], 0, 0, 0);
    }
  // C layout: col = lane&15, row = (lane>>4)*4 + i  (verified R1-R20)
#pragma unroll
  for (int mt = 0; mt < 4; ++mt)
#pragma unroll
    for (int nt = 0; nt < 2; ++nt)
#pragma unroll
      for (int i = 0; i < 4; ++i)
        tile[wm * 64 + mt * 16 + g * 4 + i][wn * 32 + nt * 16 + rl] = acc[mt][nt][i];
  __syncthreads();

  const int row = threadIdx.x >> 5;
  const int sub = threadIdx.x & 31;
#pragma unroll
  for (int p = 0; p < 8; ++p) {
    int r = p * 16 + row;
    f32x4 v = *(const f32x4*)&tile[r][sub * 4];
    *(f32x4*)(out + (size_t)(m0 + r) * V_ + n0 + sub * 4) = v;  // plain, through L2
  }
}

// ---------- launch ----------
extern "C" void kernel_launch(void* const* d_in, const int* in_sizes, int n_in,
                              void* d_out, int out_size, void* d_ws, size_t ws_size,
                              hipStream_t stream) {
  const int* ids = (const int*)d_in[0];
  const float* emb = (const float*)d_in[1];
  const float* W = (const float*)d_in[2];
  const float* Wd = (const float*)d_in[3];
  const float* bd = (const float*)d_in[4];
  float* out = (float*)d_out;
  char* ws = (char*)d_ws;

  // ws layout (bytes): [Uq 147456][hs 1 MiB][wdb 4096000]
  u32* Uq = (u32*)(ws);
  u16* hs = (u16*)(ws + 147456);
  u16* wdb = (u16*)(ws + 1196032);

  hipLaunchKernelGGL(prep_kernel, dim3(8000), dim3(256), 0, stream, Wd, wdb, W, Uq);
  hipLaunchKernelGGL(recur_kernel, dim3(NCHUNK_, B_), dim3(512), 0, stream, ids, emb,
                     Uq, hs, out + (size_t)B_ * S_ * V_);
  hipLaunchKernelGGL(decode_kernel, dim3(16000), dim3(512), 0, stream,
                     hs, wdb, bd, out);

  (void)in_sizes; (void)n_in; (void)out_size; (void)ws_size;
}

// Round 22
// 281.932 us; speedup vs baseline: 1.1940x; 1.1940x over previous
//
#include <hip/hip_runtime.h>

// ChemicalLLM: x_{t+1} = norm(relu(x + a*einsum(W,x,x))), then big decode GEMM.
//  FINAL (R20 config, best measured 282.6 us):
//  - prep: fused Wd->bf16 + symmetrized triangular int8 W quant (144 KB).
//  - recur: chunked-parallel scan (NCHUNK 32 x CHUNK 32, WARM 8; contraction
//    gamma<=0.15 => warmup IC error invisible). All of W in LDS, zero global
//    ops in the loop (emb rows pre-staged, h rows stashed in dead LDS rows,
//    bulk-stored once). 1 barrier/step, all-wave redundant epilogue.
//  - decode: 128x128 bf16 MFMA single-pass (L1-norm bound keeps error under
//    the hs-bf16 floor), XCD-aware bijective swizzle (per-XCD read set
//    1.5 MiB fits 4 MiB L2), LDS-bounce -> 512B-contiguous NT stores.
//    R21 A/B proved NT > plain (+54 us): NT protects L2 read locality.

typedef unsigned int u32;
typedef unsigned short u16;
typedef __attribute__((ext_vector_type(8))) short short8;
typedef __attribute__((ext_vector_type(4))) float f32x4;
typedef __attribute__((ext_vector_type(4))) int i32x4;

#define DECAY_ 0.1f
#define ALPHA_ 0.2f
#define EPS_ 1e-8f
#define B_ 8
#define S_ 1024
#define N_ 64
#define V_ 32000
#define NCHUNK_ 32
#define CHUNK_ 32
#define WARM_ 8
#define DEPTH_ (CHUNK_ + WARM_)  // 40
#define UBOUND_ 0.45f   // bound on max|W+W^T| (~0.35 actual; +-127 clamp guards tails)
#define NUNITS_ 288     // sum_j ((j>>3)+1) 8-byte units per k
#define UQ_DWORDS_ (NUNITS_ * 64 * 2)  // 36864 dwords = 147456 B

// ---------- bf16 helpers (manual, RNE) ----------
static __device__ __forceinline__ u16 f2bf(float f) {
  u32 u = __float_as_uint(f);
  u32 r = (u + 0x7fffu + ((u >> 16) & 1u)) >> 16;
  return (u16)r;
}

// ---------- int8 dot4 ----------
#if defined(__has_builtin)
#if __has_builtin(__builtin_amdgcn_sdot4)
#define HAVE_SDOT4 1
#endif
#endif
static __device__ __forceinline__ int dot4(int a, int b, int c) {
#ifdef HAVE_SDOT4
  return __builtin_amdgcn_sdot4(a, b, c, false);
#else
  int s = c;
  s += (int)(signed char)(a) * (int)(signed char)(b);
  s += (int)(signed char)(a >> 8) * (int)(signed char)(b >> 8);
  s += (int)(signed char)(a >> 16) * (int)(signed char)(b >> 16);
  s += (int)(a >> 24) * (int)(b >> 24);
  return s;
#endif
}

static __device__ __forceinline__ float wave_max64(float v) {
#pragma unroll
  for (int m = 1; m < 64; m <<= 1) v = fmaxf(v, __shfl_xor(v, m, 64));
  return v;
}

// ---------- prep (fused): Wd -> bf16 (all blocks) + symmetrized W quant (blocks<64) ----------
__global__ void prep_kernel(const float* __restrict__ Wd, u16* __restrict__ wdb,
                            const float* __restrict__ W, u32* __restrict__ Uq) {
  int idx = blockIdx.x * blockDim.x + threadIdx.x;  // 8000*256 = 2048000
  wdb[idx] = f2bf(Wd[idx]);
  if (blockIdx.x < 64) {
    const int j = blockIdx.x;
    const int m = j >> 3;
    const int off8 = j + 4 * m * (m - 1) + (j & 7) * m;
    const int cnt = 2 * (m + 1) * 64;  // dwords for this j
    const float s = 127.0f / UBOUND_;
    for (int d = threadIdx.x; d < cnt; d += 256) {
      int q4 = d >> 6;   // dword-in-column: i = 4*q4 + e
      int k = d & 63;
      u32 pk = 0;
#pragma unroll
      for (int e = 0; e < 4; ++e) {
        int i = 4 * q4 + e;
        float v = 0.0f;
        if (i < j)
          v = W[((size_t)i * N_ + j) * N_ + k] + W[((size_t)j * N_ + i) * N_ + k];
        else if (i == j)
          v = W[((size_t)j * N_ + j) * N_ + k];
        int qi = (int)rintf(v * s);
        qi = qi > 127 ? 127 : (qi < -127 ? -127 : qi);
        pk |= ((u32)qi & 0xffu) << (8 * e);
      }
      int dst = 2 * ((off8 + (q4 >> 1)) * 64 + k) + (q4 & 1);
      Uq[dst] = pk;
    }
  }
}

// ---------- recurrence: grid (NCHUNK, B), 512 threads (8 waves, 2/SIMD) ----------
__global__ __launch_bounds__(512, 2) void recur_kernel(
    const int* __restrict__ ids, const float* __restrict__ emb,
    const u32* __restrict__ Uq,
    u16* __restrict__ hs, float* __restrict__ outHT) {
  const int b = blockIdx.y;
  const int chunk = blockIdx.x;
  const int lane = threadIdx.x & 63;  // k in dot phase
  const int w = threadIdx.x >> 6;     // wave 0..7, owns j in {w+8m}

  const int t0 = chunk * CHUNK_;                 // first step this chunk OWNS
  const int ts = (chunk == 0) ? 0 : t0 - WARM_;  // warmup start (h=0 IC exact at t=0)
  const int tend = t0 + CHUNK_;
  const int len = tend - ts;                     // 32 (chunk 0) or 40

  __shared__ int2 lw2[NUNITS_ * 64];  // 144 KB: ALL of W (triangular symmetrized)
  __shared__ float part[2][8][64];    // double-buffered raw partials (4 KB)
  __shared__ float erow[DEPTH_][64];  // relu'd emb rows; DEAD PREFIX reused as u16 h-rows
  __shared__ float emax[DEPTH_];      // their maxes

  const float sW = UBOUND_ * (1.0f / 127.0f);

  {
    const i32x4* src = (const i32x4*)Uq;
    i32x4* dst = (i32x4*)lw2;
    for (int ii = threadIdx.x; ii < UQ_DWORDS_ / 4; ii += 512) dst[ii] = src[ii];
  }
  for (int r = w; r < len; r += 8) {
    int id = ids[b * S_ + ts + r];
    float v = fmaxf(emb[(size_t)id * N_ + lane], 0.0f);
    erow[r][lane] = v;
    float m = wave_max64(v);
    if (lane == 0) emax[r] = m;
  }
  __syncthreads();

  float xk, smul;
  u32 pk;
  {
    xk = erow[0][lane];
    float bnd = fmaxf(emax[0], 1e-20f);
    smul = bnd * (1.0f / 127.0f) * sW;
    float inv = 127.0f / bnd;
    float u = xk * inv;
    float u0 = __shfl(u, (lane & 15) * 4 + 0, 64);
    float u1 = __shfl(u, (lane & 15) * 4 + 1, 64);
    float u2 = __shfl(u, (lane & 15) * 4 + 2, 64);
    float u3 = __shfl(u, (lane & 15) * 4 + 3, 64);
    pk = (u32)(int)rintf(u0) | ((u32)(int)rintf(u1) << 8) |
         ((u32)(int)rintf(u2) << 16) | ((u32)(int)rintf(u3) << 24);
  }

  for (int t = ts; t < tend; ++t) {
    const int sidx = t - ts;
    int xr[16];
#pragma unroll
    for (int q = 0; q < 16; ++q) xr[q] = __builtin_amdgcn_readlane((int)pk, q);
    float pf = 0.0f;
#pragma unroll
    for (int m = 0; m < 8; ++m) {
      const int j = w + 8 * m;
      const int off8 = j + 4 * m * (m - 1) + w * m;
      int a = 0;
#pragma unroll
      for (int u = 0; u <= m; ++u) {
        int2 v = lw2[(off8 + u) * 64 + lane];
        a = dot4(xr[2 * u], v.x, a);
        a = dot4(xr[2 * u + 1], v.y, a);
      }
      float xj = __uint_as_float(
          __builtin_amdgcn_readlane(__float_as_uint(xk), j));
      pf += (float)a * xj;
    }
    part[t & 1][w][lane] = pf;
    __syncthreads();

    float iact = 0.0f;
#pragma unroll
    for (int q = 0; q < 8; ++q) iact += part[t & 1][q][lane];
    float xact = fmaxf(fmaf(ALPHA_ * smul, iact, xk), 0.0f);
    float s = xact;
#pragma unroll
    for (int m = 1; m < 64; m <<= 1) s += __shfl_xor(s, m, 64);
    float rS = 1.0f / (s + EPS_);
    float h = xact * rS;

    if (w == 0 && t >= t0) {
      ((u16*)&erow[t - t0][0])[lane] = f2bf(h);
      if (t == S_ - 1) outHT[b * N_ + lane] = h;
    }

    int nidx = (sidx + 1 < len) ? sidx + 1 : len - 1;
    float pcur = erow[nidx][lane];
    float xn = fmaf(1.0f - DECAY_, h, pcur);
    float nbnd = (1.0f - DECAY_) + emax[nidx];
    float inv = 127.0f / nbnd;
    float u = xn * inv;
    float u0 = __shfl(u, (lane & 15) * 4 + 0, 64);
    float u1 = __shfl(u, (lane & 15) * 4 + 1, 64);
    float u2 = __shfl(u, (lane & 15) * 4 + 2, 64);
    float u3 = __shfl(u, (lane & 15) * 4 + 3, 64);
    pk = (u32)(int)rintf(u0) | ((u32)(int)rintf(u1) << 8) |
         ((u32)(int)rintf(u2) << 16) | ((u32)(int)rintf(u3) << 24);
    smul = nbnd * (1.0f / 127.0f) * sW;
    xk = xn;
  }

  __syncthreads();
  {
    int r = threadIdx.x >> 4;
    int l4 = (threadIdx.x & 15) * 4;
    uint2 v = *(const uint2*)((const u16*)&erow[r][0] + l4);
    *(uint2*)(hs + ((size_t)b * S_ + t0 + r) * N_ + l4) = v;
  }
}

// ---------- decode: 128x128 bf16 MFMA + XCD swizzle + LDS-bounce NT stores ----------
__global__ __launch_bounds__(512, 2) void decode_kernel(
    const u16* __restrict__ hs, const u16* __restrict__ wd,
    const float* __restrict__ bd, float* __restrict__ out) {
  const int bid = blockIdx.x;
  const int xcd = bid & 7;
  const int rank = bid >> 3;              // 0..1999
  const int orig = xcd * 2000 + rank;     // n-major: orig = nblk*64 + mblk
  const int n0 = (orig >> 6) * 128;
  const int m0 = (orig & 63) * 128;

  const int lane = threadIdx.x & 63;
  const int w = threadIdx.x >> 6;
  const int wm = w >> 2, wn = w & 3;
  const int nw = n0 + wn * 32;
  const int mw = m0 + wm * 64;
  const int kg = (lane >> 4) * 8;
  const int rl = lane & 15;
  const int g = lane >> 4;

  __shared__ float tile[128][132];

  short8 bfr[2][2];
#pragma unroll
  for (int nt = 0; nt < 2; ++nt) {
    int v = nw + nt * 16 + rl;
#pragma unroll
    for (int ks = 0; ks < 2; ++ks)
      bfr[nt][ks] = *(const short8*)(wd + (size_t)v * N_ + ks * 32 + kg);
  }
  short8 a[4][2];
#pragma unroll
  for (int mt = 0; mt < 4; ++mt) {
    int row = mw + mt * 16 + rl;
#pragma unroll
    for (int ks = 0; ks < 2; ++ks)
      a[mt][ks] = *(const short8*)(hs + (size_t)row * N_ + ks * 32 + kg);
  }
  f32x4 acc[4][2];
#pragma unroll
  for (int nt = 0; nt < 2; ++nt) {
    float bdv = bd[nw + nt * 16 + rl];
#pragma unroll
    for (int mt = 0; mt < 4; ++mt) acc[mt][nt] = {bdv, bdv, bdv, bdv};
  }
#pragma unroll
  for (int mt = 0; mt < 4; ++mt)
#pragma unroll
    for (int nt = 0; nt < 2; ++nt) {
      acc[mt][nt] =
          __builtin_amdgcn_mfma_f32_16x16x32_bf16(a[mt][0], bfr[nt][0], acc[mt][nt], 0, 0, 0);
      acc[mt][nt] =
          __builtin_amdgcn_mfma_f32_16x16x32_bf16(a[mt][1], bfr[nt][1], acc[mt][nt], 0, 0, 0);
    }
  // C layout: col = lane&15, row = (lane>>4)*4 + i  (verified R1-R21)
#pragma unroll
  for (int mt = 0; mt < 4; ++mt)
#pragma unroll
    for (int nt = 0; nt < 2; ++nt)
#pragma unroll
      for (int i = 0; i < 4; ++i)
        tile[wm * 64 + mt * 16 + g * 4 + i][wn * 32 + nt * 16 + rl] = acc[mt][nt][i];
  __syncthreads();

  const int row = threadIdx.x >> 5;
  const int sub = threadIdx.x & 31;
#pragma unroll
  for (int p = 0; p < 8; ++p) {
    int r = p * 16 + row;
    f32x4 v = *(const f32x4*)&tile[r][sub * 4];
    __builtin_nontemporal_store(v, (f32x4*)(out + (size_t)(m0 + r) * V_ + n0 + sub * 4));
  }
}

// ---------- launch ----------
extern "C" void kernel_launch(void* const* d_in, const int* in_sizes, int n_in,
                              void* d_out, int out_size, void* d_ws, size_t ws_size,
                              hipStream_t stream) {
  const int* ids = (const int*)d_in[0];
  const float* emb = (const float*)d_in[1];
  const float* W = (const float*)d_in[2];
  const float* Wd = (const float*)d_in[3];
  const float* bd = (const float*)d_in[4];
  float* out = (float*)d_out;
  char* ws = (char*)d_ws;

  // ws layout (bytes): [Uq 147456][hs 1 MiB][wdb 4096000]
  u32* Uq = (u32*)(ws);
  u16* hs = (u16*)(ws + 147456);
  u16* wdb = (u16*)(ws + 1196032);

  hipLaunchKernelGGL(prep_kernel, dim3(8000), dim3(256), 0, stream, Wd, wdb, W, Uq);
  hipLaunchKernelGGL(recur_kernel, dim3(NCHUNK_, B_), dim3(512), 0, stream, ids, emb,
                     Uq, hs, out + (size_t)B_ * S_ * V_);
  hipLaunchKernelGGL(decode_kernel, dim3(16000), dim3(512), 0, stream,
                     hs, wdb, bd, out);

  (void)in_sizes; (void)n_in; (void)out_size; (void)ws_size;
}